// Round 20
// baseline (45.613 us; speedup 1.0000x reference)
//
#include <hip/hip_runtime.h>
#include <hip/hip_fp16.h>

// Unsharp-mask: out = img + param * (img - gaussblur25(img)), param = 5*(tanh(f[b,0])*.5+.5)
// img: (16,3,512,512) fp32. Output: [out (12582912 fp32)] ++ [param (16 fp32)].
//
// R20 = R19 (champion 34.8us) with HYBRID H-pass:
//   rows  0..47: Toeplitz MFMA (12 tiles, 3/wave, transposed product ->
//                one b64 writeback per tile per lane; layout verified R17/R18)
//   rows 48..87: dot2 on the VALU pipe (320 slots), executed BETWEEN the
//                MFMA issues and their writebacks so the matrix-pipe latency
//                hides under the dot2 stream.
// Stage with load-first prologue + per-slot edge path, packed-f16 V,
// LDS-center epilogue, XCD swizzle: all as R19.

#define RADIUS 12
#define KS     25
#define TILE   64
#define PT     88
#define TA_LD  104                   // tileA f16 stride (208B)
#define TB_LD  72                    // tmpB  f16 stride (144B)
#define IMG_W  512
#define IMG_H  512
#define PLANE  (IMG_W * IMG_H)
#define NPLANE 48

#define N_STAGE (PT * 11)            // 968 8px slots
#define N_H2    (40 * 8)             // dot2 slots: rows 48..87

// Normalized 25-tap Gaussian, sigma=5
__device__ __constant__ float GW[KS] = {
    0.00453456f, 0.00718308f, 0.01093238f, 0.01598625f, 0.02245983f,
    0.03031760f, 0.03931982f, 0.04899550f, 0.05865827f, 0.06747307f,
    0.07456928f, 0.07918039f, 0.08077993f, 0.07918039f, 0.07456928f,
    0.06747307f, 0.05865827f, 0.04899550f, 0.03931982f, 0.03031760f,
    0.02245983f, 0.01598625f, 0.01093238f, 0.00718308f, 0.00453456f
};

__device__ __forceinline__ int reflect512(int i) {
    i = (i < 0) ? -i : i;
    return (i >= 512) ? (1022 - i) : i;
}

typedef _Float16 h2_t __attribute__((ext_vector_type(2)));
typedef _Float16 f16x8 __attribute__((ext_vector_type(8)));
typedef float f32x4 __attribute__((ext_vector_type(4)));

__device__ __forceinline__ unsigned h2u(__half2 h) {
    union { __half2 h; unsigned u; } x; x.h = h; return x.u;
}
__device__ __forceinline__ __half2 u2h(unsigned u) {
    union { unsigned u; __half2 h; } x; x.u = u; return x.h;
}
__device__ __forceinline__ float u_lo(unsigned u) {
    return __half2float(__low2half(u2h(u)));
}
__device__ __forceinline__ float u_hi(unsigned u) {
    return __half2float(__high2half(u2h(u)));
}

#if __has_builtin(__builtin_amdgcn_fdot2)
__device__ __forceinline__ float fdot2u(unsigned a, unsigned b, float c) {
    union { unsigned u; h2_t h; } ua, ub;
    ua.u = a; ub.u = b;
    return __builtin_amdgcn_fdot2(ua.h, ub.h, c, false);
}
#else
__device__ __forceinline__ float fdot2u(unsigned a, unsigned b, float c) {
    return c + u_lo(a) * u_lo(b) + u_hi(a) * u_hi(b);
}
#endif

__global__ __launch_bounds__(256) void usm_fused_kernel(
    const float* __restrict__ img, const float* __restrict__ feat,
    float* __restrict__ out, float* __restrict__ out_param)
{
    __shared__ __half tileA[PT][TA_LD];   // 88x104 f16 = 17.9 KB
    __shared__ __half tmpB[PT][TB_LD];    // 88x72  f16 = 12.4 KB

    // ---- bijective XCD swizzle: XCD k owns 6 contiguous z-planes ----
    const int bid  = blockIdx.x + 8 * blockIdx.y + 64 * blockIdx.z;   // 0..3071
    const int swz  = (bid & 7) * 384 + (bid >> 3);
    const int bx   = swz & 7;
    const int by   = (swz >> 3) & 7;
    const int zc   = swz >> 6;

    const int tid = threadIdx.x;
    const int tx0 = bx * TILE, ty0 = by * TILE;
    const int b   = zc / 3;
    const float* __restrict__ src = img + (size_t)zc * PLANE;

    const int lane = tid & 63, wid = tid >> 6;
    const int r16 = lane & 15, kg = lane >> 4;

    // ================= Stage: ISSUE LOADS FIRST (T14-lite) =================
    float4 sva[4], svb[4];
#pragma unroll
    for (int it = 0; it < 4; ++it) {
        const int li = tid + it * 256;
        if (it < 3 || li < N_STAGE) {
            const int py = li / 11, s = li - py * 11;
            const int gy = reflect512(ty0 - RADIUS + py);
            const float* __restrict__ rowp = src + (size_t)gy * IMG_W;
            const int gx = tx0 - RADIUS + s * 8;
            if (gx >= 0 && gx + 7 <= 511) {           // per-slot fast path
                sva[it] = *(const float4*)(rowp + gx);
                svb[it] = *(const float4*)(rowp + gx + 4);
            } else {
                float4 va, vb;
                va.x = rowp[reflect512(gx)];     va.y = rowp[reflect512(gx + 1)];
                va.z = rowp[reflect512(gx + 2)]; va.w = rowp[reflect512(gx + 3)];
                vb.x = rowp[reflect512(gx + 4)]; vb.y = rowp[reflect512(gx + 5)];
                vb.z = rowp[reflect512(gx + 6)]; vb.w = rowp[reflect512(gx + 7)];
                sva[it] = va; svb[it] = vb;
            }
        }
    }

    // ---- weight tables + param + MFMA Toeplitz frags (hide under loads) ----
    unsigned W2[12];
#pragma unroll
    for (int m = 0; m < 12; ++m)
        W2[m] = h2u(__floats2half2_rn(GW[2 * m], GW[2 * m + 1]));
    const unsigned WE = h2u(__floats2half2_rn(GW[24], 0.f));
    const unsigned WO = h2u(__floats2half2_rn(0.f, GW[24]));

    __half2 GWh2[KS];
#pragma unroll
    for (int k = 0; k < KS; ++k)
        GWh2[k] = __floats2half2_rn(GW[k], GW[k]);

    // Toeplitz A-operand (verified R18): X[m][k] = GW[k-m], X2[m][k] = GW[32+k-m]
    f16x8 X1, X2;
#pragma unroll
    for (int i = 0; i < 8; ++i) {
        const int k = kg * 8 + i;
        const int d1 = k - r16;
        X1[i] = (d1 >= 0 && d1 < KS) ? (_Float16)GW[d1] : (_Float16)0.f;
        const int d2 = 32 + k - r16;
        X2[i] = (d2 < KS) ? (_Float16)GW[d2] : (_Float16)0.f;
    }

    const float param = (tanhf(feat[b * 8]) * 0.5f + 0.5f) * 5.0f;

    // ---- stage write: pack f16 -> LDS ----
#pragma unroll
    for (int it = 0; it < 4; ++it) {
        const int li = tid + it * 256;
        if (it < 3 || li < N_STAGE) {
            const int py = li / 11, s = li - py * 11;
            uint4 pk;
            pk.x = h2u(__floats2half2_rn(sva[it].x, sva[it].y));
            pk.y = h2u(__floats2half2_rn(sva[it].z, sva[it].w));
            pk.z = h2u(__floats2half2_rn(svb[it].x, svb[it].y));
            pk.w = h2u(__floats2half2_rn(svb[it].z, svb[it].w));
            *(uint4*)&tileA[py][s * 8] = pk;
        }
    }
    __syncthreads();

    // ========== Hybrid Horizontal ==========
    // (a) MFMA: rows 0..47 = 12 tiles, 3 per wave; issue now, write back later.
    f32x4 dmf0 = {0.f, 0.f, 0.f, 0.f}, dmf1 = dmf0, dmf2 = dmf0;
#pragma unroll
    for (int j = 0; j < 3; ++j) {
        const int t = wid + j * 4;                  // 0..11
        const int py0 = (t >> 2) * 16, c0 = (t & 3) * 16;
        const f16x8 Y1 = *(const f16x8*)&tileA[py0 + r16][c0 + kg * 8];
        const f16x8 Y2 = *(const f16x8*)&tileA[py0 + r16][c0 + 32];
        f32x4 d = {0.f, 0.f, 0.f, 0.f};
        d = __builtin_amdgcn_mfma_f32_16x16x32_f16(X2, Y2, d, 0, 0, 0);
        d = __builtin_amdgcn_mfma_f32_16x16x32_f16(X1, Y1, d, 0, 0, 0);
        if (j == 0) dmf0 = d; else if (j == 1) dmf1 = d; else dmf2 = d;
    }

    // (b) dot2: rows 48..87 (320 slots) -- runs while MFMAs complete.
#pragma unroll
    for (int it = 0; it < 2; ++it) {
        const int li = tid + it * 256;
        if (it < 1 || li < N_H2) {
            const int py = 48 + (li >> 3), g = li & 7;
            const uint4 qa = *(const uint4*)&tileA[py][g * 8];
            const uint4 qb = *(const uint4*)&tileA[py][g * 8 + 8];
            const uint4 qc = *(const uint4*)&tileA[py][g * 8 + 16];
            const uint4 qd = *(const uint4*)&tileA[py][g * 8 + 24];

            unsigned P[16] = { qa.x, qa.y, qa.z, qa.w, qb.x, qb.y, qb.z, qb.w,
                               qc.x, qc.y, qc.z, qc.w, qd.x, qd.y, qd.z, qd.w };
            unsigned S[15];
#pragma unroll
            for (int i = 0; i < 15; ++i)
                S[i] = __builtin_amdgcn_alignbit(P[i + 1], P[i], 16);

            float acc[8];
#pragma unroll
            for (int h = 0; h < 4; ++h) {
                float a = 0.f;
#pragma unroll
                for (int m = 0; m < 12; ++m) a = fdot2u(P[h + m], W2[m], a);
                acc[2 * h] = fdot2u(P[h + 12], WE, a);
            }
#pragma unroll
            for (int h = 0; h < 4; ++h) {
                float a = 0.f;
#pragma unroll
                for (int m = 0; m < 12; ++m) a = fdot2u(S[h + m], W2[m], a);
                acc[2 * h + 1] = fdot2u(P[h + 12], WO, a);
            }

            uint4 pk;
            pk.x = h2u(__floats2half2_rn(acc[0], acc[1]));
            pk.y = h2u(__floats2half2_rn(acc[2], acc[3]));
            pk.z = h2u(__floats2half2_rn(acc[4], acc[5]));
            pk.w = h2u(__floats2half2_rn(acc[6], acc[7]));
            *(uint4*)&tmpB[py][g * 8] = pk;
        }
    }

    // (c) MFMA writeback (transposed layout, verified R18): lane holds
    // Hblur x = c0+4kg..+3 at data row py0+r16 -> one b64 per tile.
#pragma unroll
    for (int j = 0; j < 3; ++j) {
        const int t = wid + j * 4;
        const int py0 = (t >> 2) * 16, c0 = (t & 3) * 16;
        const f32x4 d = (j == 0) ? dmf0 : (j == 1) ? dmf1 : dmf2;
        uint2 w;
        w.x = h2u(__floats2half2_rn(d[0], d[1]));
        w.y = h2u(__floats2half2_rn(d[2], d[3]));
        *(uint2*)&tmpB[py0 + r16][c0 + kg * 4] = w;
    }
    __syncthreads();

    // ========== Vertical (packed f16) + epilogue: 4x4 micro-tile ==========
    const int tx4 = (tid & 15) * 4, ry0 = (tid >> 4) * 4;

    __half2 aP0[4], aP1[4];
#pragma unroll
    for (int d = 0; d < 4; ++d) { aP0[d] = __half2(0, 0); aP1[d] = __half2(0, 0); }

#pragma unroll
    for (int k = 0; k < KS + 3; ++k) {         // 28 b64 row reads
        const uint2 rd = *(const uint2*)&tmpB[ry0 + k][tx4];
        const __half2 p0 = u2h(rd.x), p1 = u2h(rd.y);
#pragma unroll
        for (int d = 0; d < 4; ++d) {
            const int kk = k - d;
            if (kk >= 0 && kk < KS) {
                aP0[d] = __hfma2(GWh2[kk], p0, aP0[d]);
                aP1[d] = __hfma2(GWh2[kk], p1, aP1[d]);
            }
        }
    }

    float* __restrict__ dst = out + (size_t)zc * PLANE;
#pragma unroll
    for (int d = 0; d < 4; ++d) {
        const int oy = ty0 + ry0 + d;
        const uint2 cv = *(const uint2*)&tileA[ry0 + d + RADIUS][tx4 + RADIUS];
        const float v0 = u_lo(cv.x), v1 = u_hi(cv.x), v2 = u_lo(cv.y), v3 = u_hi(cv.y);
        const float b0 = __half2float(__low2half(aP0[d])), b1 = __half2float(__high2half(aP0[d]));
        const float b2 = __half2float(__low2half(aP1[d])), b3 = __half2float(__high2half(aP1[d]));
        float4 o;
        o.x = v0 + param * (v0 - b0);
        o.y = v1 + param * (v1 - b1);
        o.z = v2 + param * (v2 - b2);
        o.w = v3 + param * (v3 - b3);
        *(float4*)(dst + (size_t)oy * IMG_W + tx0 + tx4) = o;
    }

    if (tid == 0 && bx == 0 && by == 0 && (zc - b * 3) == 0)
        out_param[b] = param;
}

extern "C" void kernel_launch(void* const* d_in, const int* in_sizes, int n_in,
                              void* d_out, int out_size, void* d_ws, size_t ws_size,
                              hipStream_t stream) {
    const float* img  = (const float*)d_in[0];
    const float* feat = (const float*)d_in[1];
    float* out       = (float*)d_out;
    float* out_param = (float*)d_out + (size_t)NPLANE * PLANE;

    usm_fused_kernel<<<dim3(8, 8, NPLANE), 256, 0, stream>>>(img, feat, out, out_param);
}

// Round 21
// 34.895 us; speedup vs baseline: 1.3072x; 1.3072x over previous
//
#include <hip/hip_runtime.h>
#include <hip/hip_fp16.h>

// Unsharp-mask: out = img + param * (img - gaussblur25(img)), param = 5*(tanh(f[b,0])*.5+.5)
// img: (16,3,512,512) fp32. Output: [out (12582912 fp32)] ++ [param (16 fp32)].
//
// R21 = R19 (champion 34.8us) with the H-pass alignbit elimination:
//   odd outputs use SHIFTED WEIGHT pairs W2O[m]=(GW[2m-1],GW[2m]) against the
//   same aligned data pairs P[h+m] -- no v_alignbit, no S[] array (was 15/slot,
//   ~28% of H instructions). Even outputs: W2E[m]=(GW[2m],GW[2m+1]), GW[25]=0.
//   Identical products and summation order -> bit-identical results.
// Also: epilogue center-reads hoisted before the V loop (LDS latency hides
// under hfma2 stream). Everything else identical to R19.

#define RADIUS 12
#define KS     25
#define TILE   64
#define PT     88
#define TA_LD  104                   // tileA f16 stride (208B)
#define TB_LD  72                    // tmpB  f16 stride (144B)
#define IMG_W  512
#define IMG_H  512
#define PLANE  (IMG_W * IMG_H)
#define NPLANE 48

#define N_STAGE (PT * 11)            // 968 8px slots

// Normalized 25-tap Gaussian, sigma=5
__device__ __constant__ float GW[KS] = {
    0.00453456f, 0.00718308f, 0.01093238f, 0.01598625f, 0.02245983f,
    0.03031760f, 0.03931982f, 0.04899550f, 0.05865827f, 0.06747307f,
    0.07456928f, 0.07918039f, 0.08077993f, 0.07918039f, 0.07456928f,
    0.06747307f, 0.05865827f, 0.04899550f, 0.03931982f, 0.03031760f,
    0.02245983f, 0.01598625f, 0.01093238f, 0.00718308f, 0.00453456f
};

__device__ __forceinline__ int reflect512(int i) {
    i = (i < 0) ? -i : i;
    return (i >= 512) ? (1022 - i) : i;
}

typedef _Float16 h2_t __attribute__((ext_vector_type(2)));

__device__ __forceinline__ unsigned h2u(__half2 h) {
    union { __half2 h; unsigned u; } x; x.h = h; return x.u;
}
__device__ __forceinline__ __half2 u2h(unsigned u) {
    union { unsigned u; __half2 h; } x; x.u = u; return x.h;
}
__device__ __forceinline__ float u_lo(unsigned u) {
    return __half2float(__low2half(u2h(u)));
}
__device__ __forceinline__ float u_hi(unsigned u) {
    return __half2float(__high2half(u2h(u)));
}

#if __has_builtin(__builtin_amdgcn_fdot2)
__device__ __forceinline__ float fdot2u(unsigned a, unsigned b, float c) {
    union { unsigned u; h2_t h; } ua, ub;
    ua.u = a; ub.u = b;
    return __builtin_amdgcn_fdot2(ua.h, ub.h, c, false);
}
#else
__device__ __forceinline__ float fdot2u(unsigned a, unsigned b, float c) {
    return c + u_lo(a) * u_lo(b) + u_hi(a) * u_hi(b);
}
#endif

__global__ __launch_bounds__(256) void usm_fused_kernel(
    const float* __restrict__ img, const float* __restrict__ feat,
    float* __restrict__ out, float* __restrict__ out_param)
{
    __shared__ __half tileA[PT][TA_LD];   // 88x104 f16 = 17.9 KB
    __shared__ __half tmpB[PT][TB_LD];    // 88x72  f16 = 12.4 KB

    // ---- bijective XCD swizzle: XCD k owns 6 contiguous z-planes ----
    const int bid  = blockIdx.x + 8 * blockIdx.y + 64 * blockIdx.z;   // 0..3071
    const int swz  = (bid & 7) * 384 + (bid >> 3);
    const int bx   = swz & 7;
    const int by   = (swz >> 3) & 7;
    const int zc   = swz >> 6;

    const int tid = threadIdx.x;
    const int tx0 = bx * TILE, ty0 = by * TILE;
    const int b   = zc / 3;
    const float* __restrict__ src = img + (size_t)zc * PLANE;

    // ================= Stage: ISSUE LOADS FIRST (T14-lite) =================
    float4 sva[4], svb[4];
#pragma unroll
    for (int it = 0; it < 4; ++it) {
        const int li = tid + it * 256;
        if (it < 3 || li < N_STAGE) {
            const int py = li / 11, s = li - py * 11;
            const int gy = reflect512(ty0 - RADIUS + py);
            const float* __restrict__ rowp = src + (size_t)gy * IMG_W;
            const int gx = tx0 - RADIUS + s * 8;
            if (gx >= 0 && gx + 7 <= 511) {           // per-slot fast path
                sva[it] = *(const float4*)(rowp + gx);
                svb[it] = *(const float4*)(rowp + gx + 4);
            } else {                                   // reflect (2/11 slots, edge blocks only)
                float4 va, vb;
                va.x = rowp[reflect512(gx)];     va.y = rowp[reflect512(gx + 1)];
                va.z = rowp[reflect512(gx + 2)]; va.w = rowp[reflect512(gx + 3)];
                vb.x = rowp[reflect512(gx + 4)]; vb.y = rowp[reflect512(gx + 5)];
                vb.z = rowp[reflect512(gx + 6)]; vb.w = rowp[reflect512(gx + 7)];
                sva[it] = va; svb[it] = vb;
            }
        }
    }

    // ---- weight tables + param: computed while stage loads are in flight ----
    // Even pairs: W2E[m] = (GW[2m], GW[2m+1]), GW[25]=0.
    // Odd  pairs: W2O[m] = (GW[2m-1], GW[2m]), GW[-1]=0.
    unsigned W2E[13], W2O[13];
#pragma unroll
    for (int m = 0; m < 13; ++m) {
        const float we_lo = GW[2 * m];
        const float we_hi = (2 * m + 1 < KS) ? GW[2 * m + 1] : 0.f;
        W2E[m] = h2u(__floats2half2_rn(we_lo, we_hi));
        const float wo_lo = (2 * m - 1 >= 0) ? GW[2 * m - 1] : 0.f;
        const float wo_hi = GW[2 * m];
        W2O[m] = h2u(__floats2half2_rn(wo_lo, wo_hi));
    }

    __half2 GWh2[KS];
#pragma unroll
    for (int k = 0; k < KS; ++k)
        GWh2[k] = __floats2half2_rn(GW[k], GW[k]);

    const float param = (tanhf(feat[b * 8]) * 0.5f + 0.5f) * 5.0f;

    // ---- stage write: pack f16 -> LDS ----
#pragma unroll
    for (int it = 0; it < 4; ++it) {
        const int li = tid + it * 256;
        if (it < 3 || li < N_STAGE) {
            const int py = li / 11, s = li - py * 11;
            uint4 pk;
            pk.x = h2u(__floats2half2_rn(sva[it].x, sva[it].y));
            pk.y = h2u(__floats2half2_rn(sva[it].z, sva[it].w));
            pk.z = h2u(__floats2half2_rn(svb[it].x, svb[it].y));
            pk.w = h2u(__floats2half2_rn(svb[it].z, svb[it].w));
            *(uint4*)&tileA[py][s * 8] = pk;
        }
    }
    __syncthreads();

    // ================= Horizontal via dot2 (no alignbit): 704 slots =========
#pragma unroll
    for (int it = 0; it < 3; ++it) {
        const int li = tid + it * 256;
        if (it < 2 || li < PT * (TILE / 8)) {
            const int py = li >> 3, g = li & 7;
            const uint4 qa = *(const uint4*)&tileA[py][g * 8];
            const uint4 qb = *(const uint4*)&tileA[py][g * 8 + 8];
            const uint4 qc = *(const uint4*)&tileA[py][g * 8 + 16];
            const uint4 qd = *(const uint4*)&tileA[py][g * 8 + 24];

            unsigned P[16] = { qa.x, qa.y, qa.z, qa.w, qb.x, qb.y, qb.z, qb.w,
                               qc.x, qc.y, qc.z, qc.w, qd.x, qd.y, qd.z, qd.w };

            float acc[8];
#pragma unroll
            for (int h = 0; h < 4; ++h) {              // even outputs o = 2h
                float a = 0.f;
#pragma unroll
                for (int m = 0; m < 13; ++m) a = fdot2u(P[h + m], W2E[m], a);
                acc[2 * h] = a;
            }
#pragma unroll
            for (int h = 0; h < 4; ++h) {              // odd outputs o = 2h+1
                float a = 0.f;
#pragma unroll
                for (int m = 0; m < 13; ++m) a = fdot2u(P[h + m], W2O[m], a);
                acc[2 * h + 1] = a;
            }

            uint4 pk;
            pk.x = h2u(__floats2half2_rn(acc[0], acc[1]));
            pk.y = h2u(__floats2half2_rn(acc[2], acc[3]));
            pk.z = h2u(__floats2half2_rn(acc[4], acc[5]));
            pk.w = h2u(__floats2half2_rn(acc[6], acc[7]));
            *(uint4*)&tmpB[py][g * 8] = pk;
        }
    }
    __syncthreads();

    // ========== Vertical (packed f16) + epilogue: 4x4 micro-tile ==========
    const int tx4 = (tid & 15) * 4, ry0 = (tid >> 4) * 4;

    // center values: issue LDS reads early, consume after V loop
    uint2 cv[4];
#pragma unroll
    for (int d = 0; d < 4; ++d)
        cv[d] = *(const uint2*)&tileA[ry0 + d + RADIUS][tx4 + RADIUS];

    __half2 aP0[4], aP1[4];
#pragma unroll
    for (int d = 0; d < 4; ++d) { aP0[d] = __half2(0, 0); aP1[d] = __half2(0, 0); }

#pragma unroll
    for (int k = 0; k < KS + 3; ++k) {         // 28 b64 row reads
        const uint2 rd = *(const uint2*)&tmpB[ry0 + k][tx4];
        const __half2 p0 = u2h(rd.x), p1 = u2h(rd.y);
#pragma unroll
        for (int d = 0; d < 4; ++d) {
            const int kk = k - d;
            if (kk >= 0 && kk < KS) {
                aP0[d] = __hfma2(GWh2[kk], p0, aP0[d]);
                aP1[d] = __hfma2(GWh2[kk], p1, aP1[d]);
            }
        }
    }

    float* __restrict__ dst = out + (size_t)zc * PLANE;
#pragma unroll
    for (int d = 0; d < 4; ++d) {
        const int oy = ty0 + ry0 + d;
        const float v0 = u_lo(cv[d].x), v1 = u_hi(cv[d].x);
        const float v2 = u_lo(cv[d].y), v3 = u_hi(cv[d].y);
        const float b0 = __half2float(__low2half(aP0[d])), b1 = __half2float(__high2half(aP0[d]));
        const float b2 = __half2float(__low2half(aP1[d])), b3 = __half2float(__high2half(aP1[d]));
        float4 o;
        o.x = v0 + param * (v0 - b0);
        o.y = v1 + param * (v1 - b1);
        o.z = v2 + param * (v2 - b2);
        o.w = v3 + param * (v3 - b3);
        *(float4*)(dst + (size_t)oy * IMG_W + tx0 + tx4) = o;
    }

    if (tid == 0 && bx == 0 && by == 0 && (zc - b * 3) == 0)
        out_param[b] = param;
}

extern "C" void kernel_launch(void* const* d_in, const int* in_sizes, int n_in,
                              void* d_out, int out_size, void* d_ws, size_t ws_size,
                              hipStream_t stream) {
    const float* img  = (const float*)d_in[0];
    const float* feat = (const float*)d_in[1];
    float* out       = (float*)d_out;
    float* out_param = (float*)d_out + (size_t)NPLANE * PLANE;

    usm_fused_kernel<<<dim3(8, 8, NPLANE), 256, 0, stream>>>(img, feat, out, out_param);
}

// Round 22
// 34.882 us; speedup vs baseline: 1.3077x; 1.0004x over previous
//
#include <hip/hip_runtime.h>
#include <hip/hip_fp16.h>

// Unsharp-mask: out = img + param * (img - gaussblur25(img)), param = 5*(tanh(f[b,0])*.5+.5)
// img: (16,3,512,512) fp32. Output: [out (12582912 fp32)] ++ [param (16 fp32)].
//
// R22 = R21 (34.8us champion) + IN-PLACE LDS (tmpB deleted):
//   H holds its outputs in registers across a barrier and writes back into
//   tileA cols 0..63; V reads tileA. LDS 31.2 -> 17.9 KB -> 8 blocks/CU
//   (was ~5 allowed, ~3 resident) for cross-block phase overlap.
//   Epilogue center values are read from tileA RIGHT AFTER the stage barrier
//   (before the in-place writeback clobbers cols 12..63).
// All else identical to R21: load-first stage, per-slot edge path,
// W2E/W2O dot2 H (no alignbit), packed-f16 V, XCD swizzle.

#define RADIUS 12
#define KS     25
#define TILE   64
#define PT     88
#define TA_LD  104                   // tileA f16 stride (208B)
#define IMG_W  512
#define IMG_H  512
#define PLANE  (IMG_W * IMG_H)
#define NPLANE 48

#define N_STAGE (PT * 11)            // 968 8px slots
#define N_H     (PT * (TILE / 8))    // 704 8-output slots

// Normalized 25-tap Gaussian, sigma=5
__device__ __constant__ float GW[KS] = {
    0.00453456f, 0.00718308f, 0.01093238f, 0.01598625f, 0.02245983f,
    0.03031760f, 0.03931982f, 0.04899550f, 0.05865827f, 0.06747307f,
    0.07456928f, 0.07918039f, 0.08077993f, 0.07918039f, 0.07456928f,
    0.06747307f, 0.05865827f, 0.04899550f, 0.03931982f, 0.03031760f,
    0.02245983f, 0.01598625f, 0.01093238f, 0.00718308f, 0.00453456f
};

__device__ __forceinline__ int reflect512(int i) {
    i = (i < 0) ? -i : i;
    return (i >= 512) ? (1022 - i) : i;
}

typedef _Float16 h2_t __attribute__((ext_vector_type(2)));

__device__ __forceinline__ unsigned h2u(__half2 h) {
    union { __half2 h; unsigned u; } x; x.h = h; return x.u;
}
__device__ __forceinline__ __half2 u2h(unsigned u) {
    union { unsigned u; __half2 h; } x; x.u = u; return x.h;
}
__device__ __forceinline__ float u_lo(unsigned u) {
    return __half2float(__low2half(u2h(u)));
}
__device__ __forceinline__ float u_hi(unsigned u) {
    return __half2float(__high2half(u2h(u)));
}

#if __has_builtin(__builtin_amdgcn_fdot2)
__device__ __forceinline__ float fdot2u(unsigned a, unsigned b, float c) {
    union { unsigned u; h2_t h; } ua, ub;
    ua.u = a; ub.u = b;
    return __builtin_amdgcn_fdot2(ua.h, ub.h, c, false);
}
#else
__device__ __forceinline__ float fdot2u(unsigned a, unsigned b, float c) {
    return c + u_lo(a) * u_lo(b) + u_hi(a) * u_hi(b);
}
#endif

__device__ __forceinline__ uint4 h_slot(const __half (*tA)[TA_LD], int py, int g,
                                        const unsigned* W2E, const unsigned* W2O) {
    const uint4 qa = *(const uint4*)&tA[py][g * 8];
    const uint4 qb = *(const uint4*)&tA[py][g * 8 + 8];
    const uint4 qc = *(const uint4*)&tA[py][g * 8 + 16];
    const uint4 qd = *(const uint4*)&tA[py][g * 8 + 24];

    unsigned P[16] = { qa.x, qa.y, qa.z, qa.w, qb.x, qb.y, qb.z, qb.w,
                       qc.x, qc.y, qc.z, qc.w, qd.x, qd.y, qd.z, qd.w };

    float acc[8];
#pragma unroll
    for (int h = 0; h < 4; ++h) {              // even outputs o = 2h
        float a = 0.f;
#pragma unroll
        for (int m = 0; m < 13; ++m) a = fdot2u(P[h + m], W2E[m], a);
        acc[2 * h] = a;
    }
#pragma unroll
    for (int h = 0; h < 4; ++h) {              // odd outputs o = 2h+1
        float a = 0.f;
#pragma unroll
        for (int m = 0; m < 13; ++m) a = fdot2u(P[h + m], W2O[m], a);
        acc[2 * h + 1] = a;
    }

    uint4 pk;
    pk.x = h2u(__floats2half2_rn(acc[0], acc[1]));
    pk.y = h2u(__floats2half2_rn(acc[2], acc[3]));
    pk.z = h2u(__floats2half2_rn(acc[4], acc[5]));
    pk.w = h2u(__floats2half2_rn(acc[6], acc[7]));
    return pk;
}

__global__ __launch_bounds__(256) void usm_fused_kernel(
    const float* __restrict__ img, const float* __restrict__ feat,
    float* __restrict__ out, float* __restrict__ out_param)
{
    __shared__ __half tileA[PT][TA_LD];   // 88x104 f16 = 17.9 KB (only LDS buffer)

    // ---- bijective XCD swizzle: XCD k owns 6 contiguous z-planes ----
    const int bid  = blockIdx.x + 8 * blockIdx.y + 64 * blockIdx.z;   // 0..3071
    const int swz  = (bid & 7) * 384 + (bid >> 3);
    const int bx   = swz & 7;
    const int by   = (swz >> 3) & 7;
    const int zc   = swz >> 6;

    const int tid = threadIdx.x;
    const int tx0 = bx * TILE, ty0 = by * TILE;
    const int b   = zc / 3;
    const float* __restrict__ src = img + (size_t)zc * PLANE;

    // ================= Stage: ISSUE LOADS FIRST (T14-lite) =================
    float4 sva[4], svb[4];
#pragma unroll
    for (int it = 0; it < 4; ++it) {
        const int li = tid + it * 256;
        if (it < 3 || li < N_STAGE) {
            const int py = li / 11, s = li - py * 11;
            const int gy = reflect512(ty0 - RADIUS + py);
            const float* __restrict__ rowp = src + (size_t)gy * IMG_W;
            const int gx = tx0 - RADIUS + s * 8;
            if (gx >= 0 && gx + 7 <= 511) {           // per-slot fast path
                sva[it] = *(const float4*)(rowp + gx);
                svb[it] = *(const float4*)(rowp + gx + 4);
            } else {                                   // reflect (edge blocks only)
                float4 va, vb;
                va.x = rowp[reflect512(gx)];     va.y = rowp[reflect512(gx + 1)];
                va.z = rowp[reflect512(gx + 2)]; va.w = rowp[reflect512(gx + 3)];
                vb.x = rowp[reflect512(gx + 4)]; vb.y = rowp[reflect512(gx + 5)];
                vb.z = rowp[reflect512(gx + 6)]; vb.w = rowp[reflect512(gx + 7)];
                sva[it] = va; svb[it] = vb;
            }
        }
    }

    // ---- weight tables + param: computed while stage loads fly ----
    unsigned W2E[13], W2O[13];
#pragma unroll
    for (int m = 0; m < 13; ++m) {
        const float we_lo = GW[2 * m];
        const float we_hi = (2 * m + 1 < KS) ? GW[2 * m + 1] : 0.f;
        W2E[m] = h2u(__floats2half2_rn(we_lo, we_hi));
        const float wo_lo = (2 * m - 1 >= 0) ? GW[2 * m - 1] : 0.f;
        const float wo_hi = GW[2 * m];
        W2O[m] = h2u(__floats2half2_rn(wo_lo, wo_hi));
    }

    __half2 GWh2[KS];
#pragma unroll
    for (int k = 0; k < KS; ++k)
        GWh2[k] = __floats2half2_rn(GW[k], GW[k]);

    const float param = (tanhf(feat[b * 8]) * 0.5f + 0.5f) * 5.0f;

    // ---- stage write: pack f16 -> LDS ----
#pragma unroll
    for (int it = 0; it < 4; ++it) {
        const int li = tid + it * 256;
        if (it < 3 || li < N_STAGE) {
            const int py = li / 11, s = li - py * 11;
            uint4 pk;
            pk.x = h2u(__floats2half2_rn(sva[it].x, sva[it].y));
            pk.y = h2u(__floats2half2_rn(sva[it].z, sva[it].w));
            pk.z = h2u(__floats2half2_rn(svb[it].x, svb[it].y));
            pk.w = h2u(__floats2half2_rn(svb[it].z, svb[it].w));
            *(uint4*)&tileA[py][s * 8] = pk;
        }
    }
    __syncthreads();

    // ---- epilogue center values: read BEFORE in-place writeback clobbers ----
    const int tx4 = (tid & 15) * 4, ry0 = (tid >> 4) * 4;
    uint2 cv[4];
#pragma unroll
    for (int d = 0; d < 4; ++d)
        cv[d] = *(const uint2*)&tileA[ry0 + d + RADIUS][tx4 + RADIUS];

    // ---- H compute: 704 slots held in regs ----
    const int li1 = tid + 256, li2 = tid + 512;
    const bool act2 = (li2 < N_H);                 // tid < 192
    const uint4 h0 = h_slot(tileA, tid >> 3, tid & 7, W2E, W2O);
    const uint4 h1 = h_slot(tileA, li1 >> 3, li1 & 7, W2E, W2O);
    const uint4 h2w = act2 ? h_slot(tileA, li2 >> 3, li2 & 7, W2E, W2O)
                           : make_uint4(0, 0, 0, 0);
    __syncthreads();

    // ---- in-place write-back into tileA cols 0..63 ----
    *(uint4*)&tileA[tid >> 3][(tid & 7) * 8] = h0;
    *(uint4*)&tileA[li1 >> 3][(li1 & 7) * 8] = h1;
    if (act2) *(uint4*)&tileA[li2 >> 3][(li2 & 7) * 8] = h2w;
    __syncthreads();

    // ========== Vertical (packed f16) + epilogue: 4x4 micro-tile ==========
    __half2 aP0[4], aP1[4];
#pragma unroll
    for (int d = 0; d < 4; ++d) { aP0[d] = __half2(0, 0); aP1[d] = __half2(0, 0); }

#pragma unroll
    for (int k = 0; k < KS + 3; ++k) {         // 28 b64 row reads
        const uint2 rd = *(const uint2*)&tileA[ry0 + k][tx4];
        const __half2 p0 = u2h(rd.x), p1 = u2h(rd.y);
#pragma unroll
        for (int d = 0; d < 4; ++d) {
            const int kk = k - d;
            if (kk >= 0 && kk < KS) {
                aP0[d] = __hfma2(GWh2[kk], p0, aP0[d]);
                aP1[d] = __hfma2(GWh2[kk], p1, aP1[d]);
            }
        }
    }

    float* __restrict__ dst = out + (size_t)zc * PLANE;
#pragma unroll
    for (int d = 0; d < 4; ++d) {
        const int oy = ty0 + ry0 + d;
        const float v0 = u_lo(cv[d].x), v1 = u_hi(cv[d].x);
        const float v2 = u_lo(cv[d].y), v3 = u_hi(cv[d].y);
        const float b0 = __half2float(__low2half(aP0[d])), b1 = __half2float(__high2half(aP0[d]));
        const float b2 = __half2float(__low2half(aP1[d])), b3 = __half2float(__high2half(aP1[d]));
        float4 o;
        o.x = v0 + param * (v0 - b0);
        o.y = v1 + param * (v1 - b1);
        o.z = v2 + param * (v2 - b2);
        o.w = v3 + param * (v3 - b3);
        *(float4*)(dst + (size_t)oy * IMG_W + tx0 + tx4) = o;
    }

    if (tid == 0 && bx == 0 && by == 0 && (zc - b * 3) == 0)
        out_param[b] = param;
}

extern "C" void kernel_launch(void* const* d_in, const int* in_sizes, int n_in,
                              void* d_out, int out_size, void* d_ws, size_t ws_size,
                              hipStream_t stream) {
    const float* img  = (const float*)d_in[0];
    const float* feat = (const float*)d_in[1];
    float* out       = (float*)d_out;
    float* out_param = (float*)d_out + (size_t)NPLANE * PLANE;

    usm_fused_kernel<<<dim3(8, 8, NPLANE), 256, 0, stream>>>(img, feat, out, out_param);
}